// Round 6
// baseline (4780.798 us; speedup 1.0000x reference)
//
#include <hip/hip_runtime.h>
#include <stdint.h>

// Forbid mul+add contraction: distance arithmetic must match the numpy
// reference bit-for-bit (argmax / radius-compare are discontinuous).
// MLP math uses explicit fmaf() (exact FMA is fine; only ordering matters).
#pragma clang fp contract(off)

#define NPT   16384
#define BB    8
#define SS    1024
#define KSAMP 32
#define PTOT  (BB*SS*KSAMP)   // 262144
#define NGRP  (BB*SS)         // 8192
#define R2    0.04f
#define EPSBN 1e-5f
#define INV_M 3.814697265625e-06f   // 1/262144, exact power of two

// ws layout (floats)
#define OFF_S1 0
#define OFF_Q1 64
#define OFF_S2 128
#define OFF_Q2 192
#define OFF_S3 256    // 128
#define OFF_Q3 384    // 128
#define OFF_A1 512
#define OFF_C1 576
#define OFF_A2 640
#define OFF_C2 704
#define OFF_A3 768    // 128
#define OFF_C3 896    // 128
#define OFF_ZMAX 1024                  // 8192*128 = 1048576
#define OFF_FEAT (1024 + 1048576)      // 6*262144 = 1572864  (total ~10.5 MB)

typedef float f32x2 __attribute__((ext_vector_type(2)));

// ---------------------------------------------------------------------------
// helpers
// ---------------------------------------------------------------------------
__device__ __forceinline__ float wave_sum(float v) {
#pragma unroll
  for (int off = 32; off; off >>= 1) v += __shfl_xor(v, off);
  return v;  // butterfly: all lanes hold identical total
}

// Canonical GCN wave64 max reduction in VALU-speed DPP (no DS hops).
// bound_ctrl=1 fills 0 for invalid lanes: harmless, inputs are >= 0.
__device__ __forceinline__ float wave_max_dpp(float x) {
  int v = __float_as_int(x), t;
  t = __builtin_amdgcn_update_dpp(0, v, 0x111, 0xf, 0xf, true);  // row_shr:1
  v = __float_as_int(fmaxf(__int_as_float(v), __int_as_float(t)));
  t = __builtin_amdgcn_update_dpp(0, v, 0x112, 0xf, 0xf, true);  // row_shr:2
  v = __float_as_int(fmaxf(__int_as_float(v), __int_as_float(t)));
  t = __builtin_amdgcn_update_dpp(0, v, 0x114, 0xf, 0xf, true);  // row_shr:4
  v = __float_as_int(fmaxf(__int_as_float(v), __int_as_float(t)));
  t = __builtin_amdgcn_update_dpp(0, v, 0x118, 0xf, 0xf, true);  // row_shr:8
  v = __float_as_int(fmaxf(__int_as_float(v), __int_as_float(t)));
  t = __builtin_amdgcn_update_dpp(0, v, 0x142, 0xf, 0xf, true);  // row_bcast:15
  v = __float_as_int(fmaxf(__int_as_float(v), __int_as_float(t)));
  t = __builtin_amdgcn_update_dpp(0, v, 0x143, 0xf, 0xf, true);  // row_bcast:31
  v = __float_as_int(fmaxf(__int_as_float(v), __int_as_float(t)));
  return __int_as_float(__builtin_amdgcn_readlane(v, 63));
}

// Wave64 u32 MIN reduction via DPP. bound_ctrl=0 + old=0xffffffff: invalid
// lanes contribute the min identity instead of 0 (which would poison min).
__device__ __forceinline__ unsigned wave_min_u32_dpp(unsigned x) {
  unsigned v = x, t;
  t = (unsigned)__builtin_amdgcn_update_dpp(-1, (int)v, 0x111, 0xf, 0xf, false);
  v = v < t ? v : t;
  t = (unsigned)__builtin_amdgcn_update_dpp(-1, (int)v, 0x112, 0xf, 0xf, false);
  v = v < t ? v : t;
  t = (unsigned)__builtin_amdgcn_update_dpp(-1, (int)v, 0x114, 0xf, 0xf, false);
  v = v < t ? v : t;
  t = (unsigned)__builtin_amdgcn_update_dpp(-1, (int)v, 0x118, 0xf, 0xf, false);
  v = v < t ? v : t;
  t = (unsigned)__builtin_amdgcn_update_dpp(-1, (int)v, 0x142, 0xf, 0xf, false);
  v = v < t ? v : t;
  t = (unsigned)__builtin_amdgcn_update_dpp(-1, (int)v, 0x143, 0xf, 0xf, false);
  v = v < t ? v : t;
  return (unsigned)__builtin_amdgcn_readlane((int)v, 63);
}

// Wave64 SUM via DPP; total delivered as a scalar (readlane 63).
// bound_ctrl=1 (0-fill) is exact for sums (identity 0). Association order
// differs from the shfl butterfly, but stats are atomicAdd-accumulated
// across blocks (already order-free) and feed BN within tolerance.
__device__ __forceinline__ float wave_sum_dpp(float x) {
  float v = x;
  int t;
  t = __builtin_amdgcn_update_dpp(0, __float_as_int(v), 0x111, 0xf, 0xf, true);
  v += __int_as_float(t);
  t = __builtin_amdgcn_update_dpp(0, __float_as_int(v), 0x112, 0xf, 0xf, true);
  v += __int_as_float(t);
  t = __builtin_amdgcn_update_dpp(0, __float_as_int(v), 0x114, 0xf, 0xf, true);
  v += __int_as_float(t);
  t = __builtin_amdgcn_update_dpp(0, __float_as_int(v), 0x118, 0xf, 0xf, true);
  v += __int_as_float(t);
  t = __builtin_amdgcn_update_dpp(0, __float_as_int(v), 0x142, 0xf, 0xf, true);
  v += __int_as_float(t);
  t = __builtin_amdgcn_update_dpp(0, __float_as_int(v), 0x143, 0xf, 0xf, true);
  v += __int_as_float(t);
  return __int_as_float(__builtin_amdgcn_readlane(__float_as_int(v), 63));
}

// Per-32-lane-half MAX via DPP: lo = max(lanes 0..31), hi = max(32..63).
// MUST NOT 0-fill: inputs (pre-BN z) can be negative, and the lane-0
// accumulator feeds lane8->lane15->bcast15 -> a 0-fill would corrupt.
// bound_ctrl=0 with old=v: invalid lanes read their own value (max no-op).
__device__ __forceinline__ void half_max_dpp(float x, float& lo, float& hi) {
  int v = __float_as_int(x), t;
  t = __builtin_amdgcn_update_dpp(v, v, 0x111, 0xf, 0xf, false);  // row_shr:1
  v = __float_as_int(fmaxf(__int_as_float(v), __int_as_float(t)));
  t = __builtin_amdgcn_update_dpp(v, v, 0x112, 0xf, 0xf, false);  // row_shr:2
  v = __float_as_int(fmaxf(__int_as_float(v), __int_as_float(t)));
  t = __builtin_amdgcn_update_dpp(v, v, 0x114, 0xf, 0xf, false);  // row_shr:4
  v = __float_as_int(fmaxf(__int_as_float(v), __int_as_float(t)));
  t = __builtin_amdgcn_update_dpp(v, v, 0x118, 0xf, 0xf, false);  // row_shr:8
  v = __float_as_int(fmaxf(__int_as_float(v), __int_as_float(t)));
  t = __builtin_amdgcn_update_dpp(v, v, 0x142, 0xf, 0xf, false);  // row_bcast:15
  v = __float_as_int(fmaxf(__int_as_float(v), __int_as_float(t)));
  lo = __int_as_float(__builtin_amdgcn_readlane(v, 31));
  hi = __int_as_float(__builtin_amdgcn_readlane(v, 63));
}

// ---------------------------------------------------------------------------
// 1) Farthest point sampling. R6: VGPR residency of the full cloud is
//    unobtainable (R0/R4/R5: allocator remats loads regardless of pins;
//    VGPR_Count 52-56 each time). REVERT to the measured-good R3 structure
//    (xy staged in LDS, z+d in regs - that pressure class IS resident) and
//    graft on everything proven since:
//    - pair-major LDS layout: slot(i,t) = {x(p0),x(p1),y(p0),y(p1)},
//      p0=(2i)*1024+t, p1=p0+1024. One ds_read_b128 per 2 points (8 instead
//      of 16 DS ops/iter) and the register pairs feed v_pk_add/mul_f32
//      directly. Per-component op order identical to scalar -> bit-exact.
//    - R4/R5's proven tail (DPP wave-max + DPP u32-min + ONE ds_atomic_max
//      u64, key=(dist_bits<<32)|~idx; winner publishes z from registers;
//      cx,cy via broadcast LDS read of the static staging buffer).
//      ~700cy vs R3's ~1400cy shuffle-chain tail.
//    Distance arithmetic order unchanged: (dx*dx+dy*dy)+dz*dz, fminf;
//    dx = x + (-cx) is bit-identical to x - cx (IEEE negation exact).
// ---------------------------------------------------------------------------
__global__ __launch_bounds__(1024)
void fps_kernel(const float* __restrict__ xyz, float* __restrict__ newxyz) {
  extern __shared__ float smem[];          // 128 KiB: float4 pairbuf[8][1024]
  __shared__ unsigned long long wkey[2];   // (dist_bits<<32) | ~idx
  __shared__ float cpub[2];                // winner's z
  const int b = blockIdx.x;
  const int t = threadIdx.x;
  const int lane = t & 63;
  const float* xb = xyz + (size_t)b * NPT * 3;

  f32x2 Z[8], D[8];
#pragma unroll
  for (int i = 0; i < 8; ++i) {
    int p0 = (2 * i) * 1024 + t, p1 = p0 + 1024;
    float x0 = xb[3 * p0], y0 = xb[3 * p0 + 1], z0 = xb[3 * p0 + 2];
    float x1 = xb[3 * p1], y1 = xb[3 * p1 + 1], z1 = xb[3 * p1 + 2];
    ((float4*)smem)[i * 1024 + t] = make_float4(x0, x1, y0, y1);
    Z[i] = (f32x2){z0, z1};
    D[i] = (f32x2){1e10f, 1e10f};
    asm volatile("" : "+v"(Z[i]));        // one-time pin (R3-proven pressure)
  }

  float cx = xb[0], cy = xb[1], cz = xb[2];   // centroid 0 (idx 0)
  if (t == 0) {
    wkey[0] = 0ull; wkey[1] = 0ull;
    float* o = newxyz + (size_t)b * SS * 3;
    o[0] = cx; o[1] = cy; o[2] = cz;
  }
  __syncthreads();                         // staging + slots visible

  // two bases so every ds_read_b128 gets an immediate offset < 64KiB
  const float4* pA = (const float4*)smem + t;         // i=0..3
  const float4* pB = (const float4*)smem + 4096 + t;  // i=4..7

  for (int it = 1; it < SS; ++it) {
    const int buf = it & 1;
    const f32x2 vx = (f32x2){-cx, -cx};
    const f32x2 vy = (f32x2){-cy, -cy};
    const f32x2 vz = (f32x2){-cz, -cz};
    float bv0 = 0.0f, bv1 = 0.0f;          // distances >= 0
#pragma unroll
    for (int i = 0; i < 8; ++i) {
      float4 s = (i < 4) ? pA[i * 1024] : pB[(i - 4) * 1024];
      f32x2 px = (f32x2){s.x, s.y};        // {x0,x1}: adjacent VGPRs, free
      f32x2 py = (f32x2){s.z, s.w};        // {y0,y1}
      f32x2 dx = px + vx;                  // == x - cx bitwise
      f32x2 dy = py + vy;
      f32x2 dz = Z[i] + vz;
      f32x2 d2 = (dx * dx + dy * dy) + dz * dz;   // matches numpy order
      float m0 = fminf(D[i].x, d2.x);
      float m1 = fminf(D[i].y, d2.y);
      D[i] = (f32x2){m0, m1};
      bv0 = fmaxf(bv0, m0);
      bv1 = fmaxf(bv1, m1);
    }
    const float bv = fmaxf(bv0, bv1);
    const float wm = wave_max_dpp(bv);      // wave max -> scalar

    // candidates: lowest own-j with d[j]==wm; grab that point's z
    unsigned cand = 0xffffffffu;
    float zc = 0.0f;
    if (bv == wm) {
      int bj = 0;
#pragma unroll
      for (int j = 15; j >= 0; --j) {       // descending -> lowest j wins
        float dj = (j & 1) ? D[j >> 1].y : D[j >> 1].x;
        if (dj == wm) {
          bj = j;
          zc = (j & 1) ? Z[j >> 1].y : Z[j >> 1].x;
        }
      }
      cand = (unsigned)(bj * 1024 + t);
    }
    const unsigned wmin = wave_min_u32_dpp(cand);  // wave's lowest cand idx
    if (lane == 0)
      atomicMax(&wkey[buf],
                ((unsigned long long)__float_as_uint(wm) << 32) |
                (unsigned long long)(unsigned)~wmin);
    __syncthreads();                        // A: block winner resolved
    const unsigned long long k = wkey[buf];
    int fi = (int)~(unsigned)k;             // winner's global point index
    fi = __builtin_amdgcn_readfirstlane(fi);
    if (t == 0) wkey[buf ^ 1] = 0ull;       // reset other buffer (epoch-safe)
    if (cand == (unsigned)fi) cpub[buf] = zc;  // unique owner publishes z
    // cx,cy from the static staging buffer (no barrier needed - read-only)
    {
      const int jj = fi >> 10, tt = fi & 1023;
      const int base = ((jj >> 1) * 1024 + tt) * 4 + (jj & 1);
      cx = smem[base];                      // x component (broadcast read)
      cy = smem[base + 2];                  // y component
    }
    __syncthreads();                        // B: z published
    cz = cpub[buf];
    if (t == 0) {
      float* o = newxyz + ((size_t)b * SS + it) * 3;
      o[0] = cx; o[1] = cy; o[2] = cz;
    }
  }
}

// ---------------------------------------------------------------------------
// 2) Ball query + gather (fused): one wave per centroid, ascending-index scan
//    with ballot == ref's sort+slice. feat is channel-major [6][PTOT].
// ---------------------------------------------------------------------------
__global__ __launch_bounds__(256, 2)
void ballq_kernel(const float* __restrict__ xyz, const float* __restrict__ pts,
                  const float* __restrict__ newxyz, float* __restrict__ feat) {
  const int lane = threadIdx.x & 63;
  const int c = blockIdx.x * 4 + (threadIdx.x >> 6);  // 0..8191
  const int b = c >> 10;
  const float* xb = xyz + (size_t)b * NPT * 3;
  const float* pb = pts + (size_t)b * NPT * 3;
  const float cx = newxyz[3 * c], cy = newxyz[3 * c + 1], cz = newxyz[3 * c + 2];
  const int base = c * KSAMP;
  const uint64_t ltm = (1ull << lane) - 1ull;

  int cnt = 0, firstp = 0;
  bool haveFirst = false;
  for (int p0 = 0; p0 < NPT && cnt < KSAMP; p0 += 64) {
    int p = p0 + lane;
    float px = xb[3 * p], py = xb[3 * p + 1], pz = xb[3 * p + 2];
    float dx = cx - px, dy = cy - py, dz = cz - pz;
    float sqr = (dx * dx + dy * dy) + dz * dz;
    bool in = (sqr <= R2);                          // !(sqr > r^2)
    uint64_t m = __ballot(in);
    if (!haveFirst && m) { firstp = p0 + (__ffsll((unsigned long long)m) - 1); haveFirst = true; }
    int rank = (int)__popcll(m & ltm);
    int slot = cnt + rank;
    if (in && slot < KSAMP) {
      int idx = base + slot;
      feat[0 * PTOT + idx] = px - cx;
      feat[1 * PTOT + idx] = py - cy;
      feat[2 * PTOT + idx] = pz - cz;
      feat[3 * PTOT + idx] = pb[3 * p];
      feat[4 * PTOT + idx] = pb[3 * p + 1];
      feat[5 * PTOT + idx] = pb[3 * p + 2];
    }
    cnt += (int)__popcll(m);
  }
  if (cnt < KSAMP) {  // pad with first in-ball point (center itself qualifies)
    int slot = cnt + lane;
    if (slot < KSAMP) {
      int idx = base + slot;
      float px = xb[3 * firstp], py = xb[3 * firstp + 1], pz = xb[3 * firstp + 2];
      feat[0 * PTOT + idx] = px - cx;
      feat[1 * PTOT + idx] = py - cy;
      feat[2 * PTOT + idx] = pz - cz;
      feat[3 * PTOT + idx] = pb[3 * firstp];
      feat[4 * PTOT + idx] = pb[3 * firstp + 1];
      feat[5 * PTOT + idx] = pb[3 * firstp + 2];
    }
  }
}

// ---------------------------------------------------------------------------
// 3) stats of layer-1 pre-activations. Per-thread s[64],q[64] (cheap here:
//    only 6 FMA per channel). Block-reduce -> global atomics.
// ---------------------------------------------------------------------------
__global__ __launch_bounds__(256, 2)
void mlp1s_kernel(const float* __restrict__ feat, const float* __restrict__ w0,
                  const float* __restrict__ b0, float* __restrict__ stats) {
  float s[64], q[64];
#pragma unroll
  for (int o = 0; o < 64; ++o) { s[o] = 0.0f; q[o] = 0.0f; }
  int gid = blockIdx.x * 256 + threadIdx.x;
  for (int p = gid; p < PTOT; p += 256 * 256) {
    float f[6];
#pragma unroll
    for (int ch = 0; ch < 6; ++ch) f[ch] = feat[ch * PTOT + p];
#pragma unroll
    for (int o = 0; o < 64; ++o) {
      float z = b0[o];
#pragma unroll
      for (int i = 0; i < 6; ++i) z = fmaf(w0[o * 6 + i], f[i], z);
      s[o] += z; q[o] = fmaf(z, z, q[o]);
    }
  }
  const int lane = threadIdx.x & 63;
#pragma unroll
  for (int o = 0; o < 64; ++o) { s[o] = wave_sum(s[o]); q[o] = wave_sum(q[o]); }
  __shared__ float ls[128];
  if (threadIdx.x < 128) ls[threadIdx.x] = 0.0f;
  __syncthreads();
  if (lane == 0) {
#pragma unroll
    for (int o = 0; o < 64; ++o) { atomicAdd(&ls[o], s[o]); atomicAdd(&ls[64 + o], q[o]); }
  }
  __syncthreads();
  if (threadIdx.x < 64) atomicAdd(&stats[OFF_S1 + threadIdx.x], ls[threadIdx.x]);
  else if (threadIdx.x < 128) atomicAdd(&stats[OFF_Q1 + threadIdx.x - 64], ls[threadIdx.x]);
}

// ---------------------------------------------------------------------------
// BN fold: a = g/sqrt(var+eps), c = be - a*mu   (h = relu(a*z + c))
// ---------------------------------------------------------------------------
__global__ void fin_kernel(const float* __restrict__ g, const float* __restrict__ be,
                           const float* __restrict__ s, const float* __restrict__ q,
                           float* __restrict__ A, float* __restrict__ C, int Cn) {
  int o = blockIdx.x * blockDim.x + threadIdx.x;
  if (o >= Cn) return;
  float mu = s[o] * INV_M;
  float var = q[o] * INV_M - mu * mu;
  float a = g[o] / sqrtf(var + EPSBN);
  A[o] = a;
  C[o] = be[o] - a * mu;
}

// ---------------------------------------------------------------------------
// 4) stats of layer-2 pre-activations. h1 built explicitly (unrolled o),
//    then rolled-o loop. R6: shfl butterflies (ds_bpermute, ~120cy serial
//    hops) replaced by DPP sums delivered as scalars -> conditional adds.
// ---------------------------------------------------------------------------
__global__ __launch_bounds__(256, 2)
void mlp2s_kernel(const float* __restrict__ feat,
                  const float* __restrict__ w0, const float* __restrict__ b0,
                  const float* __restrict__ w1, const float* __restrict__ b1,
                  const float* __restrict__ par, float* __restrict__ stats) {
  const float* a1 = par + OFF_A1;
  const float* c1 = par + OFF_C1;
  const int lane = threadIdx.x & 63;
  float sp = 0.0f, qp = 0.0f;          // this lane's channel (== lane)
  int gid = blockIdx.x * 256 + threadIdx.x;
  for (int p = gid; p < PTOT; p += 512 * 256) {
    float f[6];
#pragma unroll
    for (int ch = 0; ch < 6; ++ch) f[ch] = feat[ch * PTOT + p];
    float h1[64];
#pragma unroll
    for (int o = 0; o < 64; ++o) {
      float z = b0[o];
#pragma unroll
      for (int i = 0; i < 6; ++i) z = fmaf(w0[o * 6 + i], f[i], z);
      h1[o] = fmaxf(fmaf(a1[o], z, c1[o]), 0.0f);
    }
    for (int o = 0; o < 64; o += 2) {   // rolled: scalar temps only
      float z0 = b1[o], z1 = b1[o + 1];
#pragma unroll
      for (int i = 0; i < 64; ++i) {
        z0 = fmaf(w1[o * 64 + i], h1[i], z0);
        z1 = fmaf(w1[(o + 1) * 64 + i], h1[i], z1);
      }
      float s0 = wave_sum_dpp(z0), q0 = wave_sum_dpp(z0 * z0);
      float s1 = wave_sum_dpp(z1), q1 = wave_sum_dpp(z1 * z1);
      if (lane == o)     { sp += s0; qp += q0; }
      if (lane == o + 1) { sp += s1; qp += q1; }
    }
  }
  atomicAdd(&stats[OFF_S2 + lane], sp);
  atomicAdd(&stats[OFF_Q2 + lane], qp);
}

// ---------------------------------------------------------------------------
// 5) layer-3 fused: recompute h1 (per-i, no array), accumulate h2[64]
//    (i-rolled, o-unrolled), then rolled-o layer-3. R6: DPP sums + DPP
//    per-half max (old-preserve: values can be negative) replace shfl
//    butterflies. Writes zmax[g][o] (raw pre-BN max; valid because a3>0
//    makes relu(a*z+c) monotone).
// ---------------------------------------------------------------------------
__global__ __launch_bounds__(256, 2)
void mlp3f_kernel(const float* __restrict__ feat,
                  const float* __restrict__ w0, const float* __restrict__ b0,
                  const float* __restrict__ w1, const float* __restrict__ b1,
                  const float* __restrict__ w2, const float* __restrict__ b2,
                  const float* __restrict__ par, float* __restrict__ stats,
                  float* __restrict__ zmax) {
  const float* a1 = par + OFF_A1;
  const float* c1 = par + OFF_C1;
  const float* a2 = par + OFF_A2;
  const float* c2 = par + OFF_C2;
  const int lane = threadIdx.x & 63;
  float sp0 = 0.0f, qp0 = 0.0f;        // channel lane
  float sp1 = 0.0f, qp1 = 0.0f;        // channel 64+lane
  int gid = blockIdx.x * 256 + threadIdx.x;
  for (int p = gid; p < PTOT; p += 512 * 256) {
    float f[6];
#pragma unroll
    for (int ch = 0; ch < 6; ++ch) f[ch] = feat[ch * PTOT + p];
    float h2[64];
#pragma unroll
    for (int o = 0; o < 64; ++o) h2[o] = b1[o];
    for (int i = 0; i < 64; ++i) {      // rolled; h1[i] recomputed (8 instr)
      float z = b0[i];
#pragma unroll
      for (int ch = 0; ch < 6; ++ch) z = fmaf(w0[i * 6 + ch], f[ch], z);
      float h1i = fmaxf(fmaf(a1[i], z, c1[i]), 0.0f);
#pragma unroll
      for (int o = 0; o < 64; ++o) h2[o] = fmaf(w1[o * 64 + i], h1i, h2[o]);
    }
#pragma unroll
    for (int o = 0; o < 64; ++o) h2[o] = fmaxf(fmaf(a2[o], h2[o], c2[o]), 0.0f);

    const int g = p >> 5;               // this lane's group
    for (int o = 0; o < 128; o += 2) {  // rolled: scalar temps
      float z0 = b2[o], z1 = b2[o + 1];
#pragma unroll
      for (int i = 0; i < 64; ++i) {
        z0 = fmaf(w2[o * 64 + i], h2[i], z0);
        z1 = fmaf(w2[(o + 1) * 64 + i], h2[i], z1);
      }
      float s0 = wave_sum_dpp(z0), q0 = wave_sum_dpp(z0 * z0);
      float s1 = wave_sum_dpp(z1), q1 = wave_sum_dpp(z1 * z1);
      if (lane == (o & 63))       { if (o < 64) { sp0 += s0; qp0 += q0; } else { sp1 += s0; qp1 += q0; } }
      if (lane == ((o + 1) & 63)) { if (o < 64) { sp0 += s1; qp0 += q1; } else { sp1 += s1; qp1 += q1; } }
      float m0lo, m0hi, m1lo, m1hi;
      half_max_dpp(z0, m0lo, m0hi);
      half_max_dpp(z1, m1lo, m1hi);
      if ((lane & 31) == (o & 31))
        zmax[g * 128 + o]     = (lane < 32) ? m0lo : m0hi;
      if ((lane & 31) == ((o + 1) & 31))
        zmax[g * 128 + o + 1] = (lane < 32) ? m1lo : m1hi;
    }
  }
  atomicAdd(&stats[OFF_S3 + lane], sp0);
  atomicAdd(&stats[OFF_Q3 + lane], qp0);
  atomicAdd(&stats[OFF_S3 + 64 + lane], sp1);
  atomicAdd(&stats[OFF_Q3 + 64 + lane], qp1);
}

// ---------------------------------------------------------------------------
// 6) epilogue: out2[g][c] = relu(a3[c]*zmax[g][c] + c3[c])
// ---------------------------------------------------------------------------
__global__ __launch_bounds__(256, 4)
void final_out_kernel(const float* __restrict__ zmax, const float* __restrict__ par,
                      float* __restrict__ out2) {
  const float* a3 = par + OFF_A3;
  const float* c3 = par + OFF_C3;
  int idx = blockIdx.x * 256 + threadIdx.x;   // g*128 + c
  int c = idx & 127;
  out2[idx] = fmaxf(fmaf(a3[c], zmax[idx], c3[c]), 0.0f);
}

// ---------------------------------------------------------------------------
extern "C" void kernel_launch(void* const* d_in, const int* in_sizes, int n_in,
                              void* d_out, int out_size, void* d_ws, size_t ws_size,
                              hipStream_t stream) {
  const float* xyz = (const float*)d_in[0];
  const float* pts = (const float*)d_in[1];
  const float* w0  = (const float*)d_in[2];
  const float* b0  = (const float*)d_in[3];
  const float* g0  = (const float*)d_in[4];
  const float* be0 = (const float*)d_in[5];
  const float* w1  = (const float*)d_in[6];
  const float* b1  = (const float*)d_in[7];
  const float* g1  = (const float*)d_in[8];
  const float* be1 = (const float*)d_in[9];
  const float* w2  = (const float*)d_in[10];
  const float* b2  = (const float*)d_in[11];
  const float* g2  = (const float*)d_in[12];
  const float* be2 = (const float*)d_in[13];

  float* out  = (float*)d_out;
  float* nxz  = out;                 // (B,S,3)
  float* out2 = out + BB * SS * 3;   // (B,S,128)

  float* ws    = (float*)d_ws;
  float* stats = ws;                 // 512 floats, zeroed every call
  float* par   = ws;                 // params addressed via OFF_* macros
  float* zmax  = ws + OFF_ZMAX;
  float* feat  = ws + OFF_FEAT;

  hipMemsetAsync(stats, 0, 512 * sizeof(float), stream);

  // 128 KiB dynamic LDS: pair-major {x0,x1,y0,y1} staging; z+d in VGPRs
  fps_kernel<<<BB, 1024, NPT * 8, stream>>>(xyz, nxz);
  ballq_kernel<<<2048, 256, 0, stream>>>(xyz, pts, nxz, feat);

  mlp1s_kernel<<<256, 256, 0, stream>>>(feat, w0, b0, stats);
  fin_kernel<<<1, 64, 0, stream>>>(g0, be0, stats + OFF_S1, stats + OFF_Q1,
                                   par + OFF_A1, par + OFF_C1, 64);
  mlp2s_kernel<<<512, 256, 0, stream>>>(feat, w0, b0, w1, b1, par, stats);
  fin_kernel<<<1, 64, 0, stream>>>(g1, be1, stats + OFF_S2, stats + OFF_Q2,
                                   par + OFF_A2, par + OFF_C2, 64);
  mlp3f_kernel<<<512, 256, 0, stream>>>(feat, w0, b0, w1, b1, w2, b2, par, stats, zmax);
  fin_kernel<<<1, 128, 0, stream>>>(g2, be2, stats + OFF_S3, stats + OFF_Q3,
                                    par + OFF_A3, par + OFF_C3, 128);
  final_out_kernel<<<4096, 256, 0, stream>>>(zmax, par, out2);
}

// Round 7
// 2615.735 us; speedup vs baseline: 1.8277x; 1.8277x over previous
//
#include <hip/hip_runtime.h>
#include <stdint.h>

// Forbid mul+add contraction: distance arithmetic must match the numpy
// reference bit-for-bit (argmax / radius-compare are discontinuous).
// MLP math uses explicit fmaf() (exact FMA is fine; only ordering matters).
#pragma clang fp contract(off)

#define NPT   16384
#define BB    8
#define SS    1024
#define KSAMP 32
#define PTOT  (BB*SS*KSAMP)   // 262144
#define NGRP  (BB*SS)         // 8192
#define R2    0.04f
#define EPSBN 1e-5f
#define INV_M 3.814697265625e-06f   // 1/262144, exact power of two

// ws layout (floats)
#define OFF_S1 0
#define OFF_Q1 64
#define OFF_S2 128
#define OFF_Q2 192
#define OFF_S3 256    // 128
#define OFF_Q3 384    // 128
#define OFF_A1 512
#define OFF_C1 576
#define OFF_A2 640
#define OFF_C2 704
#define OFF_A3 768    // 128
#define OFF_C3 896    // 128
#define OFF_ZMAX 1024                  // 8192*128 = 1048576
#define OFF_FEAT (1024 + 1048576)      // 6*262144 = 1572864  (total ~10.5 MB)

// ---------------------------------------------------------------------------
// helpers
// ---------------------------------------------------------------------------
__device__ __forceinline__ float wave_sum(float v) {
#pragma unroll
  for (int off = 32; off; off >>= 1) v += __shfl_xor(v, off);
  return v;  // butterfly: all lanes hold identical total
}

// Canonical GCN wave64 max reduction in VALU-speed DPP (no DS hops).
// bound_ctrl=1 fills 0 for invalid lanes: harmless, inputs are >= 0.
__device__ __forceinline__ float wave_max_dpp(float x) {
  int v = __float_as_int(x), t;
  t = __builtin_amdgcn_update_dpp(0, v, 0x111, 0xf, 0xf, true);  // row_shr:1
  v = __float_as_int(fmaxf(__int_as_float(v), __int_as_float(t)));
  t = __builtin_amdgcn_update_dpp(0, v, 0x112, 0xf, 0xf, true);  // row_shr:2
  v = __float_as_int(fmaxf(__int_as_float(v), __int_as_float(t)));
  t = __builtin_amdgcn_update_dpp(0, v, 0x114, 0xf, 0xf, true);  // row_shr:4
  v = __float_as_int(fmaxf(__int_as_float(v), __int_as_float(t)));
  t = __builtin_amdgcn_update_dpp(0, v, 0x118, 0xf, 0xf, true);  // row_shr:8
  v = __float_as_int(fmaxf(__int_as_float(v), __int_as_float(t)));
  t = __builtin_amdgcn_update_dpp(0, v, 0x142, 0xf, 0xf, true);  // row_bcast:15
  v = __float_as_int(fmaxf(__int_as_float(v), __int_as_float(t)));
  t = __builtin_amdgcn_update_dpp(0, v, 0x143, 0xf, 0xf, true);  // row_bcast:31
  v = __float_as_int(fmaxf(__int_as_float(v), __int_as_float(t)));
  return __int_as_float(__builtin_amdgcn_readlane(v, 63));
}

// Wave64 u32 MIN reduction via DPP. bound_ctrl=0 + old=0xffffffff: invalid
// lanes contribute the min identity instead of 0 (which would poison min).
__device__ __forceinline__ unsigned wave_min_u32_dpp(unsigned x) {
  unsigned v = x, t;
  t = (unsigned)__builtin_amdgcn_update_dpp(-1, (int)v, 0x111, 0xf, 0xf, false);
  v = v < t ? v : t;
  t = (unsigned)__builtin_amdgcn_update_dpp(-1, (int)v, 0x112, 0xf, 0xf, false);
  v = v < t ? v : t;
  t = (unsigned)__builtin_amdgcn_update_dpp(-1, (int)v, 0x114, 0xf, 0xf, false);
  v = v < t ? v : t;
  t = (unsigned)__builtin_amdgcn_update_dpp(-1, (int)v, 0x118, 0xf, 0xf, false);
  v = v < t ? v : t;
  t = (unsigned)__builtin_amdgcn_update_dpp(-1, (int)v, 0x142, 0xf, 0xf, false);
  v = v < t ? v : t;
  t = (unsigned)__builtin_amdgcn_update_dpp(-1, (int)v, 0x143, 0xf, 0xf, false);
  v = v < t ? v : t;
  return (unsigned)__builtin_amdgcn_readlane((int)v, 63);
}

// Wave64 SUM via DPP; total delivered as a scalar (readlane 63).
// bound_ctrl=1 (0-fill) is exact for sums (identity 0).
__device__ __forceinline__ float wave_sum_dpp(float x) {
  float v = x;
  int t;
  t = __builtin_amdgcn_update_dpp(0, __float_as_int(v), 0x111, 0xf, 0xf, true);
  v += __int_as_float(t);
  t = __builtin_amdgcn_update_dpp(0, __float_as_int(v), 0x112, 0xf, 0xf, true);
  v += __int_as_float(t);
  t = __builtin_amdgcn_update_dpp(0, __float_as_int(v), 0x114, 0xf, 0xf, true);
  v += __int_as_float(t);
  t = __builtin_amdgcn_update_dpp(0, __float_as_int(v), 0x118, 0xf, 0xf, true);
  v += __int_as_float(t);
  t = __builtin_amdgcn_update_dpp(0, __float_as_int(v), 0x142, 0xf, 0xf, true);
  v += __int_as_float(t);
  t = __builtin_amdgcn_update_dpp(0, __float_as_int(v), 0x143, 0xf, 0xf, true);
  v += __int_as_float(t);
  return __int_as_float(__builtin_amdgcn_readlane(__float_as_int(v), 63));
}

// Per-32-lane-half MAX via DPP: lo = max(lanes 0..31), hi = max(32..63).
// MUST NOT 0-fill: inputs (pre-BN z) can be negative. bound_ctrl=0 with
// old=v: invalid lanes read their own value (max no-op).
__device__ __forceinline__ void half_max_dpp(float x, float& lo, float& hi) {
  int v = __float_as_int(x), t;
  t = __builtin_amdgcn_update_dpp(v, v, 0x111, 0xf, 0xf, false);  // row_shr:1
  v = __float_as_int(fmaxf(__int_as_float(v), __int_as_float(t)));
  t = __builtin_amdgcn_update_dpp(v, v, 0x112, 0xf, 0xf, false);  // row_shr:2
  v = __float_as_int(fmaxf(__int_as_float(v), __int_as_float(t)));
  t = __builtin_amdgcn_update_dpp(v, v, 0x114, 0xf, 0xf, false);  // row_shr:4
  v = __float_as_int(fmaxf(__int_as_float(v), __int_as_float(t)));
  t = __builtin_amdgcn_update_dpp(v, v, 0x118, 0xf, 0xf, false);  // row_shr:8
  v = __float_as_int(fmaxf(__int_as_float(v), __int_as_float(t)));
  t = __builtin_amdgcn_update_dpp(v, v, 0x142, 0xf, 0xf, false);  // row_bcast:15
  v = __float_as_int(fmaxf(__int_as_float(v), __int_as_float(t)));
  lo = __int_as_float(__builtin_amdgcn_readlane(v, 31));
  hi = __int_as_float(__builtin_amdgcn_readlane(v, 63));
}

// ---------------------------------------------------------------------------
// 1) Farthest point sampling. R7: R6's f32x2+float4 variant hit the
//    allocator's pathological minimum (VGPR_Count=32 -> loop-carried D/Z
//    spilled to scratch, 2.7x slower). THE body that works is R3's, verbatim
//    (scalar z[16]/d[16], float2 LDS staging, ds_read_b64 imm offsets,
//    VGPR=52, 1545us measured). ONE change vs R3: the reduce tail.
//    R3 tail was 12 serial ds_bpermute hops (~120cy each, m117) + redundant
//    per-thread 8-entry scan ~= 1400cy. Replaced with the tail proven
//    correct in R4/R5/R6 (three passing rounds): DPP wave-max + DPP
//    u32-min(candidate) + ONE ds_atomic_max_u64 (key=(dist_bits<<32)|~idx;
//    u32 order == f32 order for >=0, ~idx -> first-occurrence tie-break
//    == jnp.argmax) + winner publishes z from registers; cx,cy via
//    broadcast LDS read of the static staging buffer. ~700cy, 2 barriers.
//    Distance arithmetic order unchanged (bit-exact): (dx*dx+dy*dy)+dz*dz,
//    fminf; centroid coords bitwise copies via LDS/register publish.
// ---------------------------------------------------------------------------
__global__ __launch_bounds__(1024)
void fps_kernel(const float* __restrict__ xyz, float* __restrict__ newxyz) {
  extern __shared__ float smem[];          // 128 KiB dynamic: float2 sxy[NPT]
  float2* sxy = (float2*)smem;
  __shared__ unsigned long long wkey[2];   // (dist_bits<<32) | ~idx
  __shared__ float cpub[2];                // winner's z
  const int b = blockIdx.x;
  const int t = threadIdx.x;
  const int lane = t & 63;
  const float* xb = xyz + (size_t)b * NPT * 3;

  float z[16], d[16];
#pragma unroll
  for (int j = 0; j < 16; ++j) {
    int p = j * 1024 + t;
    float xx = xb[3 * p];
    float yy = xb[3 * p + 1];
    float zz = xb[3 * p + 2];
    sxy[p] = make_float2(xx, yy);
    z[j] = zz;
    d[j] = 1e10f;
    asm volatile("" : "+v"(z[j]));        // keep z materialized (R3-proven)
  }

  // initial centroid = point 0 (uniform broadcast loads, once)
  float cx = xb[0], cy = xb[1], cz = xb[2];
  if (t == 0) {
    wkey[0] = 0ull; wkey[1] = 0ull;
    float* o = newxyz + (size_t)b * SS * 3;
    o[0] = cx; o[1] = cy; o[2] = cz;
  }
  __syncthreads();                         // sxy + slots visible to all waves

  // two bases so every ds_read_b64 gets an immediate offset < 64KiB:
  // pA[j*1024] covers j=0..7 (byte offs 0..57344), pB likewise for j=8..15.
  const float2* pA = sxy + t;
  const float2* pB = sxy + t + 8192;

  for (int it = 1; it < SS; ++it) {
    const int buf = it & 1;
    float bv = 0.0f;                       // distances >= 0
#pragma unroll
    for (int j = 0; j < 16; ++j) {
      float2 xy = (j < 8) ? pA[j * 1024] : pB[(j - 8) * 1024];
      float dx = xy.x - cx, dy = xy.y - cy, dz = z[j] - cz;
      float d2 = (dx * dx + dy * dy) + dz * dz;   // matches numpy order
      float dm = fminf(d[j], d2);
      d[j] = dm;
      bv = fmaxf(bv, dm);                 // value-only tracking
    }
    const float wm = wave_max_dpp(bv);    // wave max -> scalar (VALU only)

    // candidates: lowest own-j with d[j]==wm; grab that point's z.
    // fmax returns an operand bitwise, so equality holds for the max.
    unsigned cand = 0xffffffffu;
    float zc = 0.0f;
    if (bv == wm) {
      int bj = 0;
#pragma unroll
      for (int j = 15; j >= 0; --j) {     // descending -> lowest j wins
        if (d[j] == wm) { bj = j; zc = z[j]; }
      }
      cand = (unsigned)(bj * 1024 + t);
    }
    const unsigned wmin = wave_min_u32_dpp(cand);  // wave's lowest cand idx
    if (lane == 0)
      atomicMax(&wkey[buf],
                ((unsigned long long)__float_as_uint(wm) << 32) |
                (unsigned long long)(unsigned)~wmin);
    __syncthreads();                      // A: block winner resolved
    const unsigned long long k = wkey[buf];
    int fi = (int)~(unsigned)k;           // winner's global point index
    fi = __builtin_amdgcn_readfirstlane(fi);
    if (t == 0) wkey[buf ^ 1] = 0ull;     // reset other buffer (epoch-safe)
    if (cand == (unsigned)fi) cpub[buf] = zc;  // unique owner publishes z
    // cx,cy from the static staging buffer (read-only, no barrier needed)
    float2 cxy = sxy[fi];                 // LDS broadcast read
    cx = cxy.x; cy = cxy.y;
    __syncthreads();                      // B: z published
    cz = cpub[buf];
    if (t == 0) {
      float* o = newxyz + ((size_t)b * SS + it) * 3;
      o[0] = cx; o[1] = cy; o[2] = cz;
    }
  }
}

// ---------------------------------------------------------------------------
// 2) Ball query + gather (fused): one wave per centroid, ascending-index scan
//    with ballot == ref's sort+slice. feat is channel-major [6][PTOT].
// ---------------------------------------------------------------------------
__global__ __launch_bounds__(256, 2)
void ballq_kernel(const float* __restrict__ xyz, const float* __restrict__ pts,
                  const float* __restrict__ newxyz, float* __restrict__ feat) {
  const int lane = threadIdx.x & 63;
  const int c = blockIdx.x * 4 + (threadIdx.x >> 6);  // 0..8191
  const int b = c >> 10;
  const float* xb = xyz + (size_t)b * NPT * 3;
  const float* pb = pts + (size_t)b * NPT * 3;
  const float cx = newxyz[3 * c], cy = newxyz[3 * c + 1], cz = newxyz[3 * c + 2];
  const int base = c * KSAMP;
  const uint64_t ltm = (1ull << lane) - 1ull;

  int cnt = 0, firstp = 0;
  bool haveFirst = false;
  for (int p0 = 0; p0 < NPT && cnt < KSAMP; p0 += 64) {
    int p = p0 + lane;
    float px = xb[3 * p], py = xb[3 * p + 1], pz = xb[3 * p + 2];
    float dx = cx - px, dy = cy - py, dz = cz - pz;
    float sqr = (dx * dx + dy * dy) + dz * dz;
    bool in = (sqr <= R2);                          // !(sqr > r^2)
    uint64_t m = __ballot(in);
    if (!haveFirst && m) { firstp = p0 + (__ffsll((unsigned long long)m) - 1); haveFirst = true; }
    int rank = (int)__popcll(m & ltm);
    int slot = cnt + rank;
    if (in && slot < KSAMP) {
      int idx = base + slot;
      feat[0 * PTOT + idx] = px - cx;
      feat[1 * PTOT + idx] = py - cy;
      feat[2 * PTOT + idx] = pz - cz;
      feat[3 * PTOT + idx] = pb[3 * p];
      feat[4 * PTOT + idx] = pb[3 * p + 1];
      feat[5 * PTOT + idx] = pb[3 * p + 2];
    }
    cnt += (int)__popcll(m);
  }
  if (cnt < KSAMP) {  // pad with first in-ball point (center itself qualifies)
    int slot = cnt + lane;
    if (slot < KSAMP) {
      int idx = base + slot;
      float px = xb[3 * firstp], py = xb[3 * firstp + 1], pz = xb[3 * firstp + 2];
      feat[0 * PTOT + idx] = px - cx;
      feat[1 * PTOT + idx] = py - cy;
      feat[2 * PTOT + idx] = pz - cz;
      feat[3 * PTOT + idx] = pb[3 * firstp];
      feat[4 * PTOT + idx] = pb[3 * firstp + 1];
      feat[5 * PTOT + idx] = pb[3 * firstp + 2];
    }
  }
}

// ---------------------------------------------------------------------------
// 3) stats of layer-1 pre-activations. Per-thread s[64],q[64] (cheap here:
//    only 6 FMA per channel). Block-reduce -> global atomics.
// ---------------------------------------------------------------------------
__global__ __launch_bounds__(256, 2)
void mlp1s_kernel(const float* __restrict__ feat, const float* __restrict__ w0,
                  const float* __restrict__ b0, float* __restrict__ stats) {
  float s[64], q[64];
#pragma unroll
  for (int o = 0; o < 64; ++o) { s[o] = 0.0f; q[o] = 0.0f; }
  int gid = blockIdx.x * 256 + threadIdx.x;
  for (int p = gid; p < PTOT; p += 256 * 256) {
    float f[6];
#pragma unroll
    for (int ch = 0; ch < 6; ++ch) f[ch] = feat[ch * PTOT + p];
#pragma unroll
    for (int o = 0; o < 64; ++o) {
      float z = b0[o];
#pragma unroll
      for (int i = 0; i < 6; ++i) z = fmaf(w0[o * 6 + i], f[i], z);
      s[o] += z; q[o] = fmaf(z, z, q[o]);
    }
  }
  const int lane = threadIdx.x & 63;
#pragma unroll
  for (int o = 0; o < 64; ++o) { s[o] = wave_sum(s[o]); q[o] = wave_sum(q[o]); }
  __shared__ float ls[128];
  if (threadIdx.x < 128) ls[threadIdx.x] = 0.0f;
  __syncthreads();
  if (lane == 0) {
#pragma unroll
    for (int o = 0; o < 64; ++o) { atomicAdd(&ls[o], s[o]); atomicAdd(&ls[64 + o], q[o]); }
  }
  __syncthreads();
  if (threadIdx.x < 64) atomicAdd(&stats[OFF_S1 + threadIdx.x], ls[threadIdx.x]);
  else if (threadIdx.x < 128) atomicAdd(&stats[OFF_Q1 + threadIdx.x - 64], ls[threadIdx.x]);
}

// ---------------------------------------------------------------------------
// BN fold: a = g/sqrt(var+eps), c = be - a*mu   (h = relu(a*z + c))
// ---------------------------------------------------------------------------
__global__ void fin_kernel(const float* __restrict__ g, const float* __restrict__ be,
                           const float* __restrict__ s, const float* __restrict__ q,
                           float* __restrict__ A, float* __restrict__ C, int Cn) {
  int o = blockIdx.x * blockDim.x + threadIdx.x;
  if (o >= Cn) return;
  float mu = s[o] * INV_M;
  float var = q[o] * INV_M - mu * mu;
  float a = g[o] / sqrtf(var + EPSBN);
  A[o] = a;
  C[o] = be[o] - a * mu;
}

// ---------------------------------------------------------------------------
// 4) stats of layer-2 pre-activations. h1 built explicitly (unrolled o),
//    then rolled-o loop. DPP sums (scalar result) -> conditional adds.
// ---------------------------------------------------------------------------
__global__ __launch_bounds__(256, 2)
void mlp2s_kernel(const float* __restrict__ feat,
                  const float* __restrict__ w0, const float* __restrict__ b0,
                  const float* __restrict__ w1, const float* __restrict__ b1,
                  const float* __restrict__ par, float* __restrict__ stats) {
  const float* a1 = par + OFF_A1;
  const float* c1 = par + OFF_C1;
  const int lane = threadIdx.x & 63;
  float sp = 0.0f, qp = 0.0f;          // this lane's channel (== lane)
  int gid = blockIdx.x * 256 + threadIdx.x;
  for (int p = gid; p < PTOT; p += 512 * 256) {
    float f[6];
#pragma unroll
    for (int ch = 0; ch < 6; ++ch) f[ch] = feat[ch * PTOT + p];
    float h1[64];
#pragma unroll
    for (int o = 0; o < 64; ++o) {
      float z = b0[o];
#pragma unroll
      for (int i = 0; i < 6; ++i) z = fmaf(w0[o * 6 + i], f[i], z);
      h1[o] = fmaxf(fmaf(a1[o], z, c1[o]), 0.0f);
    }
    for (int o = 0; o < 64; o += 2) {   // rolled: scalar temps only
      float z0 = b1[o], z1 = b1[o + 1];
#pragma unroll
      for (int i = 0; i < 64; ++i) {
        z0 = fmaf(w1[o * 64 + i], h1[i], z0);
        z1 = fmaf(w1[(o + 1) * 64 + i], h1[i], z1);
      }
      float s0 = wave_sum_dpp(z0), q0 = wave_sum_dpp(z0 * z0);
      float s1 = wave_sum_dpp(z1), q1 = wave_sum_dpp(z1 * z1);
      if (lane == o)     { sp += s0; qp += q0; }
      if (lane == o + 1) { sp += s1; qp += q1; }
    }
  }
  atomicAdd(&stats[OFF_S2 + lane], sp);
  atomicAdd(&stats[OFF_Q2 + lane], qp);
}

// ---------------------------------------------------------------------------
// 5) layer-3 fused: recompute h1 (per-i, no array), accumulate h2[64]
//    (i-rolled, o-unrolled), then rolled-o layer-3. DPP sums + DPP per-half
//    max (old-preserve: values can be negative). Writes zmax[g][o] (raw
//    pre-BN max; valid because a3>0 makes relu(a*z+c) monotone).
// ---------------------------------------------------------------------------
__global__ __launch_bounds__(256, 2)
void mlp3f_kernel(const float* __restrict__ feat,
                  const float* __restrict__ w0, const float* __restrict__ b0,
                  const float* __restrict__ w1, const float* __restrict__ b1,
                  const float* __restrict__ w2, const float* __restrict__ b2,
                  const float* __restrict__ par, float* __restrict__ stats,
                  float* __restrict__ zmax) {
  const float* a1 = par + OFF_A1;
  const float* c1 = par + OFF_C1;
  const float* a2 = par + OFF_A2;
  const float* c2 = par + OFF_C2;
  const int lane = threadIdx.x & 63;
  float sp0 = 0.0f, qp0 = 0.0f;        // channel lane
  float sp1 = 0.0f, qp1 = 0.0f;        // channel 64+lane
  int gid = blockIdx.x * 256 + threadIdx.x;
  for (int p = gid; p < PTOT; p += 512 * 256) {
    float f[6];
#pragma unroll
    for (int ch = 0; ch < 6; ++ch) f[ch] = feat[ch * PTOT + p];
    float h2[64];
#pragma unroll
    for (int o = 0; o < 64; ++o) h2[o] = b1[o];
    for (int i = 0; i < 64; ++i) {      // rolled; h1[i] recomputed (8 instr)
      float z = b0[i];
#pragma unroll
      for (int ch = 0; ch < 6; ++ch) z = fmaf(w0[i * 6 + ch], f[ch], z);
      float h1i = fmaxf(fmaf(a1[i], z, c1[i]), 0.0f);
#pragma unroll
      for (int o = 0; o < 64; ++o) h2[o] = fmaf(w1[o * 64 + i], h1i, h2[o]);
    }
#pragma unroll
    for (int o = 0; o < 64; ++o) h2[o] = fmaxf(fmaf(a2[o], h2[o], c2[o]), 0.0f);

    const int g = p >> 5;               // this lane's group
    for (int o = 0; o < 128; o += 2) {  // rolled: scalar temps
      float z0 = b2[o], z1 = b2[o + 1];
#pragma unroll
      for (int i = 0; i < 64; ++i) {
        z0 = fmaf(w2[o * 64 + i], h2[i], z0);
        z1 = fmaf(w2[(o + 1) * 64 + i], h2[i], z1);
      }
      float s0 = wave_sum_dpp(z0), q0 = wave_sum_dpp(z0 * z0);
      float s1 = wave_sum_dpp(z1), q1 = wave_sum_dpp(z1 * z1);
      if (lane == (o & 63))       { if (o < 64) { sp0 += s0; qp0 += q0; } else { sp1 += s0; qp1 += q0; } }
      if (lane == ((o + 1) & 63)) { if (o < 64) { sp0 += s1; qp0 += q1; } else { sp1 += s1; qp1 += q1; } }
      float m0lo, m0hi, m1lo, m1hi;
      half_max_dpp(z0, m0lo, m0hi);
      half_max_dpp(z1, m1lo, m1hi);
      if ((lane & 31) == (o & 31))
        zmax[g * 128 + o]     = (lane < 32) ? m0lo : m0hi;
      if ((lane & 31) == ((o + 1) & 31))
        zmax[g * 128 + o + 1] = (lane < 32) ? m1lo : m1hi;
    }
  }
  atomicAdd(&stats[OFF_S3 + lane], sp0);
  atomicAdd(&stats[OFF_Q3 + lane], qp0);
  atomicAdd(&stats[OFF_S3 + 64 + lane], sp1);
  atomicAdd(&stats[OFF_Q3 + 64 + lane], qp1);
}

// ---------------------------------------------------------------------------
// 6) epilogue: out2[g][c] = relu(a3[c]*zmax[g][c] + c3[c])
// ---------------------------------------------------------------------------
__global__ __launch_bounds__(256, 4)
void final_out_kernel(const float* __restrict__ zmax, const float* __restrict__ par,
                      float* __restrict__ out2) {
  const float* a3 = par + OFF_A3;
  const float* c3 = par + OFF_C3;
  int idx = blockIdx.x * 256 + threadIdx.x;   // g*128 + c
  int c = idx & 127;
  out2[idx] = fmaxf(fmaf(a3[c], zmax[idx], c3[c]), 0.0f);
}

// ---------------------------------------------------------------------------
extern "C" void kernel_launch(void* const* d_in, const int* in_sizes, int n_in,
                              void* d_out, int out_size, void* d_ws, size_t ws_size,
                              hipStream_t stream) {
  const float* xyz = (const float*)d_in[0];
  const float* pts = (const float*)d_in[1];
  const float* w0  = (const float*)d_in[2];
  const float* b0  = (const float*)d_in[3];
  const float* g0  = (const float*)d_in[4];
  const float* be0 = (const float*)d_in[5];
  const float* w1  = (const float*)d_in[6];
  const float* b1  = (const float*)d_in[7];
  const float* g1  = (const float*)d_in[8];
  const float* be1 = (const float*)d_in[9];
  const float* w2  = (const float*)d_in[10];
  const float* b2  = (const float*)d_in[11];
  const float* g2  = (const float*)d_in[12];
  const float* be2 = (const float*)d_in[13];

  float* out  = (float*)d_out;
  float* nxz  = out;                 // (B,S,3)
  float* out2 = out + BB * SS * 3;   // (B,S,128)

  float* ws    = (float*)d_ws;
  float* stats = ws;                 // 512 floats, zeroed every call
  float* par   = ws;                 // params addressed via OFF_* macros
  float* zmax  = ws + OFF_ZMAX;
  float* feat  = ws + OFF_FEAT;

  hipMemsetAsync(stats, 0, 512 * sizeof(float), stream);

  // 128 KiB dynamic LDS: float2 (x,y) staging; z+d in VGPRs (R3-proven)
  fps_kernel<<<BB, 1024, NPT * sizeof(float2), stream>>>(xyz, nxz);
  ballq_kernel<<<2048, 256, 0, stream>>>(xyz, pts, nxz, feat);

  mlp1s_kernel<<<256, 256, 0, stream>>>(feat, w0, b0, stats);
  fin_kernel<<<1, 64, 0, stream>>>(g0, be0, stats + OFF_S1, stats + OFF_Q1,
                                   par + OFF_A1, par + OFF_C1, 64);
  mlp2s_kernel<<<512, 256, 0, stream>>>(feat, w0, b0, w1, b1, par, stats);
  fin_kernel<<<1, 64, 0, stream>>>(g1, be1, stats + OFF_S2, stats + OFF_Q2,
                                   par + OFF_A2, par + OFF_C2, 64);
  mlp3f_kernel<<<512, 256, 0, stream>>>(feat, w0, b0, w1, b1, w2, b2, par, stats, zmax);
  fin_kernel<<<1, 128, 0, stream>>>(g2, be2, stats + OFF_S3, stats + OFF_Q3,
                                    par + OFF_A3, par + OFF_C3, 128);
  final_out_kernel<<<4096, 256, 0, stream>>>(zmax, par, out2);
}